// Round 4
// baseline (155.164 us; speedup 1.0000x reference)
//
#include <hip/hip_runtime.h>
#include <math.h>

#define KK 32
#define CC 256

// ---------------------------------------------------------------------------
// Kernel 1: A-transform (one W1 row per block, 512 blocks) + barrier init.
// A[o,k] = 0.5*rowsum_k(W1 row o) + colsum_k - 0.5*W1[o,33k]  so that
// W1 @ p == A @ mean  (pooled_ij = (i==j)? m_i : 0.5*m_i + m_j).
// Bit-identical to the R3 A-path. Block 0 zeroes the 3 grid-barrier slots.
// ---------------------------------------------------------------------------
__global__ __launch_bounds__(256) void a_init_kernel(
    const float* __restrict__ W1, float* __restrict__ A_ws,
    unsigned* __restrict__ bar)
{
    __shared__ float rowlds[1056];
    const int t = threadIdx.x;
    const int o = blockIdx.x;                 // 0..511
    if (blockIdx.x == 0 && t < 8) bar[t * 32] = 0u;   // cnt/flag pairs, 128B apart
    if (t < 64) {
        const float* wr = W1 + (size_t)o * 1024;
        #pragma unroll
        for (int u = 0; u < 4; ++u) {
            const int e = t * 16 + u * 4;
            const float4 v = *(const float4*)(wr + e);
            const int f = (e >> 5) * 33 + (e & 31);
            rowlds[f] = v.x; rowlds[f + 1] = v.y;
            rowlds[f + 2] = v.z; rowlds[f + 3] = v.w;
        }
    }
    __syncthreads();
    if (t < 32) {
        float rs = 0.f, cs = 0.f;
        #pragma unroll
        for (int j = 0; j < 32; ++j) rs += rowlds[t * 33 + j];
        #pragma unroll
        for (int i = 0; i < 32; ++i) cs += rowlds[i * 33 + t];
        A_ws[o * 32 + t] = 0.5f * rs + cs - 0.5f * rowlds[t * 34];
    }
}

// ---------------------------------------------------------------------------
// Software grid barrier: all 256 blocks co-resident (<=2 blocks/CU by LDS,
// launch_bounds(256,2) guarantees 2/CU always fit -> no deadlock).
// Agent-scope release/acquire: on gfx950 the release fence emits
// buffer_wbl2 sc1 (whole-XCD-L2 writeback), acquire emits buffer_inv —
// cache-wide, so thread-0 fence + __syncthreads covers all block threads.
// ---------------------------------------------------------------------------
__device__ __forceinline__ void grid_barrier(unsigned* cnt, unsigned* flag) {
    __syncthreads();
    if (threadIdx.x == 0) {
        __threadfence();   // release all block writes to agent scope
        const unsigned old = __hip_atomic_fetch_add(
            cnt, 1u, __ATOMIC_ACQ_REL, __HIP_MEMORY_SCOPE_AGENT);
        if (old == 255u) {
            __hip_atomic_store(flag, 1u, __ATOMIC_RELEASE, __HIP_MEMORY_SCOPE_AGENT);
        } else {
            while (__hip_atomic_load(flag, __ATOMIC_ACQUIRE,
                                     __HIP_MEMORY_SCOPE_AGENT) == 0u)
                __builtin_amdgcn_s_sleep(2);
        }
        __threadfence();   // acquire
    }
    __syncthreads();
}

// ---------------------------------------------------------------------------
// Kernel 2 (fused): 256 blocks x 256 threads, 3 grid barriers.
//  P1 (block=bm): stage raw x in xs (kept for P4), means, center into cen,
//     cov upper-tri 2x2 tiles (BIT-EXACT chain — adj>0 mask is knife-edge),
//     adj -> out region, mean -> ws.
//  P2 (block=(b,og)): h = gelu(A @ mean), 8 o's/block.
//  P3 (block=(b,ot)): e = sigmoid(W2 @ h), W2 16-row tile staged in LDS
//     (aliases cen — dead after P1), wave-uniform broadcasts, bit-exact.
//  P4 (block=bm): mask from covm sign (== adj>0, std>0), softmax, att @ xs.
// ---------------------------------------------------------------------------
__global__ __launch_bounds__(256, 2) void fused_kernel(
    const float* __restrict__ x, const float* __restrict__ W2,
    const float* __restrict__ A_ws, float* __restrict__ mean_ws,
    float* __restrict__ h_ws, float* __restrict__ e_ws,
    unsigned* __restrict__ bar, float* __restrict__ out,
    float* __restrict__ adj_out)
{
    __shared__ float xs[KK][260];          // raw x, float4-aligned, lives P1..P4
    __shared__ float cenW2[8256];          // union: cen[32][258] (P1) / W2s[16][512] (P3)
    __shared__ float covm[KK][KK + 1];     // lives P1..P4
    __shared__ float att[KK][KK + 1];
    __shared__ float part8[256];
    __shared__ float meanv[KK];
    __shared__ float stdv[KK];

    const int t  = threadIdx.x;
    const int bm = blockIdx.x;             // 0..255
    const int b  = bm >> 6, m = bm & 63;

    // ---------------- Phase 1: stats ----------------
    const float* xp = x + (size_t)bm * (KK * CC);
    #pragma unroll
    for (int s = 0; s < 8; ++s) {
        const int e = s * 1024 + t * 4;
        const float4 v = *(const float4*)(xp + e);
        *(float4*)&xs[e >> 8][e & 255] = v;
    }
    __syncthreads();
    {
        const int i = t >> 3, part = t & 7;
        float s = 0.f;
        const int c0 = part * 32;
        #pragma unroll
        for (int c = 0; c < 32; ++c) s += xs[i][c0 + c];
        part8[t] = s;
    }
    __syncthreads();
    if (t < KK) {
        float s = 0.f;
        #pragma unroll
        for (int k = 0; k < 8; ++k) s += part8[t * 8 + k];
        meanv[t] = s * (1.0f / CC);
        mean_ws[(size_t)(b * 32 + t) * 64 + m] = meanv[t];
    }
    __syncthreads();
    {
        const int r = t >> 3, c0 = (t & 7) * 32;
        const float mv = meanv[r];
        #pragma unroll
        for (int c = 0; c < 32; ++c) cenW2[r * 258 + c0 + c] = xs[r][c0 + c] - mv;
    }
    __syncthreads();
    if (t < 136) {
        int rem = t, r = 0;
        while (rem >= 16 - r) { rem -= 16 - r; ++r; }
        const int ti = r, tj = r + rem;
        const int i0 = 2 * ti, i1 = i0 + 1, j0 = 2 * tj, j1 = j0 + 1;
        float c00 = 0.f, c01 = 0.f, c10 = 0.f, c11 = 0.f;
        for (int c = 0; c < CC; c += 2) {
            const float2 a0 = *(const float2*)&cenW2[i0 * 258 + c];
            const float2 a1 = *(const float2*)&cenW2[i1 * 258 + c];
            const float2 b0 = *(const float2*)&cenW2[j0 * 258 + c];
            const float2 b1 = *(const float2*)&cenW2[j1 * 258 + c];
            // sequential fma chain per accumulator — bit-exact vs R3
            c00 += a0.x * b0.x; c00 += a0.y * b0.y;
            c01 += a0.x * b1.x; c01 += a0.y * b1.y;
            c10 += a1.x * b0.x; c10 += a1.y * b0.y;
            c11 += a1.x * b1.x; c11 += a1.y * b1.y;
        }
        c00 *= (1.0f / (CC - 1)); c01 *= (1.0f / (CC - 1));
        c10 *= (1.0f / (CC - 1)); c11 *= (1.0f / (CC - 1));
        covm[i0][j0] = c00; covm[i0][j1] = c01;
        covm[i1][j0] = c10; covm[i1][j1] = c11;
        covm[j0][i0] = c00; covm[j1][i0] = c01;
        covm[j0][i1] = c10; covm[j1][i1] = c11;
    }
    __syncthreads();
    if (t < KK) stdv[t] = sqrtf(covm[t][t]);
    __syncthreads();
    #pragma unroll
    for (int k = 0; k < 4; ++k) {
        const int pair = t + k * 256;
        const int i = pair >> 5, j = pair & 31;
        adj_out[(size_t)bm * 1024 + pair] = covm[i][j] / (stdv[i] * stdv[j]);
    }

    // ---------------- Phase 2: h = gelu(A @ mean) ----------------
    grid_barrier(&bar[0], &bar[32]);
    {
        const int b2 = bm >> 6, og = bm & 63;
        const int m2 = t & 63, q2 = t >> 6;      // q2 wave-uniform
        float mr[32];
        #pragma unroll
        for (int k = 0; k < 32; ++k)
            mr[k] = mean_ws[(size_t)(b2 * 32 + k) * 64 + m2];
        #pragma unroll
        for (int qq = 0; qq < 2; ++qq) {
            const int o = og * 8 + q2 + qq * 4;
            const float* Ar = A_ws + (size_t)o * 32;
            float a = 0.f;
            #pragma unroll
            for (int k = 0; k < 32; ++k) a += Ar[k] * mr[k];
            const float g = 0.5f * a * (1.0f + erff(a * 0.70710678118654752f));
            h_ws[(size_t)(b2 * 512 + o) * 64 + m2] = g;
        }
    }

    // ---------------- Phase 3: e = sigmoid(W2 @ h) ----------------
    grid_barrier(&bar[64], &bar[96]);
    {
        float (*W2s)[512] = (float (*)[512])cenW2;   // cen dead after P1
        const int b3 = bm >> 6, ob = (bm & 63) * 16;
        const int m3 = t & 63, ow = t >> 6;
        const float* src = W2 + (size_t)ob * 512;
        #pragma unroll
        for (int u = 0; u < 8; ++u) {
            const int e4 = t + u * 256;
            const float4 v = *(const float4*)(src + e4 * 4);
            *(float4*)&W2s[e4 >> 7][(e4 & 127) * 4] = v;
        }
        __syncthreads();
        const float* hb = h_ws + (size_t)b3 * 512 * 64 + m3;
        float acc[4] = {0.f, 0.f, 0.f, 0.f};
        const int ol = ow * 4;
        for (int c = 0; c < 512; c += 4) {
            const float hv0 = hb[(size_t)(c + 0) * 64];
            const float hv1 = hb[(size_t)(c + 1) * 64];
            const float hv2 = hb[(size_t)(c + 2) * 64];
            const float hv3 = hb[(size_t)(c + 3) * 64];
            #pragma unroll
            for (int q = 0; q < 4; ++q) {
                const float4 w = *(const float4*)&W2s[ol + q][c];  // broadcast
                acc[q] += w.x * hv0;
                acc[q] += w.y * hv1;
                acc[q] += w.z * hv2;
                acc[q] += w.w * hv3;
            }
        }
        #pragma unroll
        for (int q = 0; q < 4; ++q)
            e_ws[(size_t)(b3 * 1024 + ob + ol + q) * 64 + m3] =
                1.0f / (1.0f + expf(-acc[q]));
    }

    // ---------------- Phase 4: masked softmax + att @ x ----------------
    grid_barrier(&bar[128], &bar[160]);
    #pragma unroll
    for (int k = 0; k < 4; ++k) {
        const int pair = t + k * 256;
        const int i = pair >> 5, j = pair & 31;
        const float ev = e_ws[(size_t)(b * 1024 + pair) * 64 + m];
        att[i][j] = (covm[i][j] > 0.f) ? ev : -INFINITY;  // sign(adj)==sign(cov)
    }
    __syncthreads();
    if (t < KK) {
        float mx = -INFINITY;
        #pragma unroll
        for (int j = 0; j < KK; ++j) mx = fmaxf(mx, att[t][j]);
        float s = 0.f;
        #pragma unroll
        for (int j = 0; j < KK; ++j) {
            const float v = expf(att[t][j] - mx);
            att[t][j] = v;
            s += v;
        }
        const float inv = 1.0f / s;
        #pragma unroll
        for (int j = 0; j < KK; ++j) att[t][j] *= inv;
    }
    __syncthreads();
    {
        const int c8 = t & 31, iq = t >> 5;
        const int i0 = iq * 4;
        const int cA = 4 * c8, cB = 128 + 4 * c8;
        float4 accA[4], accB[4];
        #pragma unroll
        for (int r = 0; r < 4; ++r) {
            accA[r] = make_float4(0.f, 0.f, 0.f, 0.f);
            accB[r] = make_float4(0.f, 0.f, 0.f, 0.f);
        }
        for (int j = 0; j < KK; ++j) {
            const float4 xa = *(const float4*)&xs[j][cA];
            const float4 xb = *(const float4*)&xs[j][cB];
            #pragma unroll
            for (int r = 0; r < 4; ++r) {
                const float av = att[i0 + r][j];
                accA[r].x += av * xa.x; accA[r].y += av * xa.y;
                accA[r].z += av * xa.z; accA[r].w += av * xa.w;
                accB[r].x += av * xb.x; accB[r].y += av * xb.y;
                accB[r].z += av * xb.z; accB[r].w += av * xb.w;
            }
        }
        float* op = out + (size_t)bm * (KK * CC);
        #pragma unroll
        for (int r = 0; r < 4; ++r) {
            *(float4*)(op + (size_t)(i0 + r) * CC + cA) = accA[r];
            *(float4*)(op + (size_t)(i0 + r) * CC + cB) = accB[r];
        }
    }
}

extern "C" void kernel_launch(void* const* d_in, const int* in_sizes, int n_in,
                              void* d_out, int out_size, void* d_ws, size_t ws_size,
                              hipStream_t stream) {
    const float* x  = (const float*)d_in[0];   // (4,64,32,256)
    const float* W1 = (const float*)d_in[1];   // (512,1024)
    const float* W2 = (const float*)d_in[2];   // (1024,512)
    float* out     = (float*)d_out;                       // 2,097,152 floats
    float* adj_out = out + (size_t)4 * 64 * 32 * 256;     // +262,144 floats

    float* mean_ws = (float*)d_ws;                    // f[0      .. 8191]
    float* A_ws    = mean_ws + 8192;                  // f[8192   .. 24575]
    float* h_ws    = A_ws + 16384;                    // f[24576  .. 155647]
    float* e_ws    = h_ws + 131072;                   // f[155648 .. 417791]
    unsigned* bar  = (unsigned*)(e_ws + 262144);      // 8 x 128B slots

    a_init_kernel<<<512, 256, 0, stream>>>(W1, A_ws, bar);
    fused_kernel<<<256, 256, 0, stream>>>(x, W2, A_ws, mean_ws, h_ws, e_ws,
                                          bar, out, adj_out);
}

// Round 5
// 100.476 us; speedup vs baseline: 1.5443x; 1.5443x over previous
//
#include <hip/hip_runtime.h>
#include <math.h>

#define KK 32
#define CC 256

// ---------------------------------------------------------------------------
// Kernel 1: per-(b,m) stats. 256 blocks, 256 threads (pure — no A blocks).
// Stage x in LDS (stride 258), row means, center, cov upper-tri via 2x2
// register tiles (BIT-EXACT sequential fma chain — adj>0 mask is knife-edge),
// adj -> out region, means -> mean_ws.
// ---------------------------------------------------------------------------
__global__ __launch_bounds__(256) void prep_kernel(
    const float* __restrict__ x, float* __restrict__ mean_ws,
    float* __restrict__ adj_out)
{
    __shared__ float xs[KK][258];
    __shared__ float part8[256];
    __shared__ float meanv[KK];
    __shared__ float covm[KK][KK + 1];
    __shared__ float stdv[KK];

    const int t  = threadIdx.x;
    const int bm = blockIdx.x;            // 0..255
    const int b  = bm >> 6, m = bm & 63;
    const float* xp = x + (size_t)bm * (KK * CC);

    #pragma unroll
    for (int s = 0; s < 8; ++s) {
        const int e = s * 1024 + t * 4;
        const float4 v = *(const float4*)(xp + e);
        const int i = e >> 8, col = e & 255;
        xs[i][col] = v.x; xs[i][col + 1] = v.y;
        xs[i][col + 2] = v.z; xs[i][col + 3] = v.w;
    }
    __syncthreads();
    {
        const int i = t >> 3, part = t & 7;
        float s = 0.f;
        const int c0 = part * 32;
        #pragma unroll
        for (int c = 0; c < 32; ++c) s += xs[i][c0 + c];
        part8[t] = s;
    }
    __syncthreads();
    if (t < KK) {
        float s = 0.f;
        #pragma unroll
        for (int k = 0; k < 8; ++k) s += part8[t * 8 + k];
        meanv[t] = s * (1.0f / CC);
        mean_ws[(size_t)(b * 32 + t) * 64 + m] = meanv[t];
    }
    __syncthreads();
    {
        const int r = t >> 3, c0 = (t & 7) * 32;
        const float mv = meanv[r];
        #pragma unroll
        for (int c = 0; c < 32; ++c) xs[r][c0 + c] -= mv;
    }
    __syncthreads();
    if (t < 136) {
        int rem = t, r = 0;
        while (rem >= 16 - r) { rem -= 16 - r; ++r; }
        const int ti = r, tj = r + rem;
        const int i0 = 2 * ti, i1 = i0 + 1, j0 = 2 * tj, j1 = j0 + 1;
        float c00 = 0.f, c01 = 0.f, c10 = 0.f, c11 = 0.f;
        for (int c = 0; c < CC; c += 2) {
            const float2 a0 = *(const float2*)&xs[i0][c];
            const float2 a1 = *(const float2*)&xs[i1][c];
            const float2 b0 = *(const float2*)&xs[j0][c];
            const float2 b1 = *(const float2*)&xs[j1][c];
            // sequential fma chain per accumulator — bit-exact vs R3
            c00 += a0.x * b0.x; c00 += a0.y * b0.y;
            c01 += a0.x * b1.x; c01 += a0.y * b1.y;
            c10 += a1.x * b0.x; c10 += a1.y * b0.y;
            c11 += a1.x * b1.x; c11 += a1.y * b1.y;
        }
        c00 *= (1.0f / (CC - 1)); c01 *= (1.0f / (CC - 1));
        c10 *= (1.0f / (CC - 1)); c11 *= (1.0f / (CC - 1));
        covm[i0][j0] = c00; covm[i0][j1] = c01;
        covm[i1][j0] = c10; covm[i1][j1] = c11;
        covm[j0][i0] = c00; covm[j1][i0] = c01;
        covm[j0][i1] = c10; covm[j1][i1] = c11;
    }
    __syncthreads();
    if (t < KK) stdv[t] = sqrtf(covm[t][t]);
    __syncthreads();
    #pragma unroll
    for (int k = 0; k < 4; ++k) {
        const int pair = t + k * 256;
        const int i = pair >> 5, j = pair & 31;
        adj_out[(size_t)bm * 1024 + pair] = covm[i][j] / (stdv[i] * stdv[j]);
    }
}

// ---------------------------------------------------------------------------
// Kernel 2: A rows from W1 (bit-identical reduction order to R3's a_init:
// A[o,k] = 0.5f*rowsum_k + colsum_k - 0.5f*W1[o,33k]) computed in-block,
// then h = gelu(A @ mean). Block (og, b), 64 threads, 4 o's per block.
// ---------------------------------------------------------------------------
__global__ __launch_bounds__(64) void mlp1_kernel(
    const float* __restrict__ W1, const float* __restrict__ mean_ws,
    float* __restrict__ h_ws)
{
    __shared__ float rowlds[4][1056];   // element 32k+j of row q at [q][k*33+j]
    __shared__ float Al[4][32];
    const int t  = threadIdx.x;         // 0..63
    const int b  = blockIdx.y;
    const int ob = blockIdx.x * 4;

    const float* wr = W1 + (size_t)ob * 1024;
    #pragma unroll
    for (int u = 0; u < 16; ++u) {
        const int e4 = t + u * 64;          // float4 index over 4 rows
        const int q  = e4 >> 8;
        const int e  = (e4 & 255) * 4;
        const float4 v = *(const float4*)(wr + q * 1024 + e);
        const int f = (e >> 5) * 33 + (e & 31);
        rowlds[q][f] = v.x; rowlds[q][f + 1] = v.y;
        rowlds[q][f + 2] = v.z; rowlds[q][f + 3] = v.w;
    }
    __syncthreads();
    {
        const int k = t & 31, qh = t >> 5;
        #pragma unroll
        for (int qq = 0; qq < 2; ++qq) {
            const int q = qh + qq * 2;
            float rs = 0.f, cs = 0.f;
            #pragma unroll
            for (int j = 0; j < 32; ++j) rs += rowlds[q][k * 33 + j];
            #pragma unroll
            for (int i = 0; i < 32; ++i) cs += rowlds[q][i * 33 + k];
            Al[q][k] = 0.5f * rs + cs - 0.5f * rowlds[q][k * 34];
        }
    }
    __syncthreads();
    const int m = t;
    float mr[32];
    #pragma unroll
    for (int k = 0; k < 32; ++k) mr[k] = mean_ws[(size_t)(b * 32 + k) * 64 + m];
    #pragma unroll
    for (int q = 0; q < 4; ++q) {
        float a = 0.f;
        #pragma unroll
        for (int k = 0; k < 32; ++k) a += Al[q][k] * mr[k];   // k-ascending, bit-exact
        const float g = 0.5f * a * (1.0f + erff(a * 0.70710678118654752f));
        h_ws[(size_t)(b * 512 + ob + q) * 64 + m] = g;
    }
}

// ---------------------------------------------------------------------------
// Kernel 3: e = sigmoid(W2 @ h). Block = 16 o x 64 m (4 waves), grid (64,4).
// W2 tile in LDS, wave-uniform float4 broadcasts; h coalesced; acc chain
// c-ascending (bit-exact vs R3). NEW: e_ws layout [b][m][o], one float4
// store per thread (scattered stores instead of scattered softmax reads).
// ---------------------------------------------------------------------------
__global__ __launch_bounds__(256) void mlp2_kernel(
    const float* __restrict__ W2, const float* __restrict__ h_ws,
    float* __restrict__ e_ws)
{
    __shared__ float W2s[16][512];     // 32 KB
    const int m  = threadIdx.x;        // 0..63
    const int ow = threadIdx.y;        // 0..3
    const int b  = blockIdx.y;
    const int ob = blockIdx.x * 16;

    {
        const int t = ow * 64 + m;
        const float* src = W2 + (size_t)ob * 512;
        #pragma unroll
        for (int u = 0; u < 8; ++u) {
            const int e4 = t + u * 256;
            const float4 v = *(const float4*)(src + e4 * 4);
            *(float4*)&W2s[e4 >> 7][(e4 & 127) * 4] = v;
        }
    }
    __syncthreads();

    const float* hb = h_ws + (size_t)b * 512 * 64 + m;
    float acc[4] = {0.f, 0.f, 0.f, 0.f};
    const int ol = ow * 4;

    for (int c = 0; c < 512; c += 4) {
        const float hv0 = hb[(size_t)(c + 0) * 64];
        const float hv1 = hb[(size_t)(c + 1) * 64];
        const float hv2 = hb[(size_t)(c + 2) * 64];
        const float hv3 = hb[(size_t)(c + 3) * 64];
        #pragma unroll
        for (int q = 0; q < 4; ++q) {
            const float4 w = *(const float4*)&W2s[ol + q][c];  // broadcast
            acc[q] += w.x * hv0;
            acc[q] += w.y * hv1;
            acc[q] += w.z * hv2;
            acc[q] += w.w * hv3;
        }
    }
    float4 sv;
    sv.x = 1.0f / (1.0f + expf(-acc[0]));
    sv.y = 1.0f / (1.0f + expf(-acc[1]));
    sv.z = 1.0f / (1.0f + expf(-acc[2]));
    sv.w = 1.0f / (1.0f + expf(-acc[3]));
    *(float4*)&e_ws[(size_t)(b * 64 + m) * 1024 + ob + ol] = sv;
}

// ---------------------------------------------------------------------------
// Kernel 4: masked softmax (mask adj>0) + att @ x.  256 blocks (b,m).
// e and adj reads now fully-coalesced float4 (e layout [b][m][o]).
// ---------------------------------------------------------------------------
__global__ __launch_bounds__(256) void softmax_out_kernel(
    const float* __restrict__ x, const float* __restrict__ e_ws,
    const float* __restrict__ adj, float* __restrict__ out)
{
    __shared__ float xs[KK][260];
    __shared__ float att[KK][KK + 1];
    const int bm = blockIdx.x;
    const int b  = bm >> 6, m = bm & 63;
    const int t  = threadIdx.x;
    const float* xp = x + (size_t)bm * (KK * CC);

    #pragma unroll
    for (int s = 0; s < 8; ++s) {
        const int e = s * 1024 + t * 4;
        const float4 v = *(const float4*)(xp + e);
        *(float4*)&xs[e >> 8][e & 255] = v;
    }
    {
        const int p0 = 4 * t;
        const float4 ev4 = *(const float4*)&e_ws[(size_t)(b * 64 + m) * 1024 + p0];
        const float4 aj4 = *(const float4*)&adj[(size_t)bm * 1024 + p0];
        const int i = p0 >> 5, j0 = p0 & 31;
        att[i][j0]     = (aj4.x > 0.f) ? ev4.x : -INFINITY;
        att[i][j0 + 1] = (aj4.y > 0.f) ? ev4.y : -INFINITY;
        att[i][j0 + 2] = (aj4.z > 0.f) ? ev4.z : -INFINITY;
        att[i][j0 + 3] = (aj4.w > 0.f) ? ev4.w : -INFINITY;
    }
    __syncthreads();
    if (t < KK) {
        float mx = -INFINITY;
        #pragma unroll
        for (int j = 0; j < KK; ++j) mx = fmaxf(mx, att[t][j]);
        float s = 0.f;
        #pragma unroll
        for (int j = 0; j < KK; ++j) {
            const float v = expf(att[t][j] - mx);
            att[t][j] = v;
            s += v;
        }
        const float inv = 1.0f / s;
        #pragma unroll
        for (int j = 0; j < KK; ++j) att[t][j] *= inv;
    }
    __syncthreads();

    const int c8 = t & 31, iq = t >> 5;
    const int i0 = iq * 4;
    const int cA = 4 * c8, cB = 128 + 4 * c8;
    float4 accA[4], accB[4];
    #pragma unroll
    for (int r = 0; r < 4; ++r) {
        accA[r] = make_float4(0.f, 0.f, 0.f, 0.f);
        accB[r] = make_float4(0.f, 0.f, 0.f, 0.f);
    }
    for (int j = 0; j < KK; ++j) {
        const float4 xa = *(const float4*)&xs[j][cA];
        const float4 xb = *(const float4*)&xs[j][cB];
        #pragma unroll
        for (int r = 0; r < 4; ++r) {
            const float av = att[i0 + r][j];
            accA[r].x += av * xa.x; accA[r].y += av * xa.y;
            accA[r].z += av * xa.z; accA[r].w += av * xa.w;
            accB[r].x += av * xb.x; accB[r].y += av * xb.y;
            accB[r].z += av * xb.z; accB[r].w += av * xb.w;
        }
    }
    float* op = out + (size_t)bm * (KK * CC);
    #pragma unroll
    for (int r = 0; r < 4; ++r) {
        *(float4*)(op + (size_t)(i0 + r) * CC + cA) = accA[r];
        *(float4*)(op + (size_t)(i0 + r) * CC + cB) = accB[r];
    }
}

extern "C" void kernel_launch(void* const* d_in, const int* in_sizes, int n_in,
                              void* d_out, int out_size, void* d_ws, size_t ws_size,
                              hipStream_t stream) {
    const float* x  = (const float*)d_in[0];   // (4,64,32,256)
    const float* W1 = (const float*)d_in[1];   // (512,1024)
    const float* W2 = (const float*)d_in[2];   // (1024,512)
    float* out     = (float*)d_out;                       // 2,097,152 floats
    float* adj_out = out + (size_t)4 * 64 * 32 * 256;     // +262,144 floats

    float* mean_ws = (float*)d_ws;                    // 4*32*64   =   8,192
    float* h_ws    = mean_ws + 8192;                  // 4*512*64  = 131,072
    float* e_ws    = h_ws + 131072;                   // 4*64*1024 = 262,144

    prep_kernel<<<256, 256, 0, stream>>>(x, mean_ws, adj_out);
    mlp1_kernel<<<dim3(128, 4), 64, 0, stream>>>(W1, mean_ws, h_ws);
    mlp2_kernel<<<dim3(64, 4), dim3(64, 4), 0, stream>>>(W2, h_ws, e_ws);
    softmax_out_kernel<<<256, 256, 0, stream>>>(x, e_ws, adj_out, out);
}